// Round 5
// baseline (179.192 us; speedup 1.0000x reference)
//
#include <hip/hip_runtime.h>
#include <stdint.h>

// Gemma4PatchEmbed round 5: two kernels.
// prep: pixels -> bf16 A (16384x768 row-major) via LDS transpose (coalesced both
//       sides), w_proj -> bf16 Wb.
// gemm: 128x128 tile, BK=32, ring-of-3 LDS buffers staged with global_load_lds
//       (fire-and-forget: compiler cannot sink it), raw s_barrier with
//       s_waitcnt vmcnt(4) -- 8 loads stay in flight across every barrier.
//       XOR-swizzled DMA slots make DMA writes AND ds_read_b128 fragment reads
//       conflict-free (exact b128 floor). Fused pos-table gather epilogue.

typedef __attribute__((ext_vector_type(8))) short bfrag_t;        // MFMA A/B operand
typedef __attribute__((ext_vector_type(4))) float f4_t;            // MFMA C/D
typedef __attribute__((ext_vector_type(8))) unsigned short u16x8;
typedef __attribute__((ext_vector_type(4))) unsigned short u16x4;

#define V_POS 10240

__device__ __forceinline__ unsigned short f2bf(float f) {
    unsigned int u = __float_as_uint(f);
    u += 0x7fffu + ((u >> 16) & 1u);          // RNE fp32 -> bf16
    return (unsigned short)(u >> 16);
}

__device__ __forceinline__ void async_ld16(const void* g, void* l) {
    // global DMA -> LDS, dest = wave-uniform base + lane*16, vmcnt-tracked
    __builtin_amdgcn_global_load_lds(
        (const __attribute__((address_space(1))) void*)g,
        (__attribute__((address_space(3))) void*)l, 16, 0, 0);
}

// ---------------------------------------------------------------------------
// Kernel 1: prep. blocks [0,512): one (b,ph) m-row group: pixels -> LDS bf16
// transpose (stride 776 = conflict-balanced) -> A row-major writeback.
// blocks [512,800): w_proj -> bf16.
// ---------------------------------------------------------------------------
__global__ __launch_bounds__(256) void prep_kernel(
    const float* __restrict__ px, const float* __restrict__ wp,
    unsigned short* __restrict__ A, unsigned short* __restrict__ Wb)
{
    __shared__ unsigned short T[32 * 776];    // 48.5 KB
    int bid = blockIdx.x, tid = threadIdx.x;
    if (bid < 512) {
        int b = bid >> 5, ph = bid & 31;
        const float* pxb = px + ((size_t)b * 3 * 512 + (size_t)ph * 16) * 512;
#pragma unroll 6
        for (int it = 0; it < 24; ++it) {
            int idx = it * 256 + tid;         // float4 index in 96 KB region
            int c = idx >> 11, rem = idx & 2047, hl = rem >> 7, w4 = rem & 127;
            float4 v = *(const float4*)(pxb + (size_t)c * 262144 + hl * 512 + (w4 << 2));
            int pw  = w4 >> 2;                // patch column = local A row
            int pxo = (w4 & 3) << 2;
            int k   = c * 256 + hl * 16 + pxo;
            u16x4 o;
            o[0] = f2bf(2.f * v.x - 1.f);
            o[1] = f2bf(2.f * v.y - 1.f);
            o[2] = f2bf(2.f * v.z - 1.f);
            o[3] = f2bf(2.f * v.w - 1.f);
            *(u16x4*)&T[pw * 776 + k] = o;
        }
        __syncthreads();
        int r = tid >> 3, p = tid & 7;        // 8 threads per A row
        unsigned short* Arow = A + ((size_t)bid * 32 + r) * 768;
        const unsigned short* Trow = T + r * 776;
#pragma unroll 4
        for (int j = 0; j < 12; ++j) {
            int co = (p + 8 * j) << 3;        // 16-B piece
            *(u16x8*)(Arow + co) = *(const u16x8*)(Trow + co);
        }
    } else {
        long idx = (long)(bid - 512) * 256 + tid;   // 0..73727, 8 floats each
        const float4* s = (const float4*)(wp + (idx << 3));
        float4 v0 = s[0], v1 = s[1];
        u16x8 o;
        o[0] = f2bf(v0.x); o[1] = f2bf(v0.y); o[2] = f2bf(v0.z); o[3] = f2bf(v0.w);
        o[4] = f2bf(v1.x); o[5] = f2bf(v1.y); o[6] = f2bf(v1.z); o[7] = f2bf(v1.w);
        *(u16x8*)(Wb + (idx << 3)) = o;
    }
}

// ---------------------------------------------------------------------------
// Kernel 2: GEMM 16384x768x768 + fused pos-embed epilogue.
// 768 blocks (exactly 3/CU), 256 threads, 48 KB LDS (3-buffer ring).
// ---------------------------------------------------------------------------
__global__ __launch_bounds__(256, 3) void gemm_kernel(
    const unsigned short* __restrict__ A, const unsigned short* __restrict__ Bt,
    const int* __restrict__ pos_ids, const unsigned int* __restrict__ pad_in,
    const float* __restrict__ pos_table, float* __restrict__ out)
{
    __shared__ unsigned short LDS[3 * 8192];  // buf r: A @ r*8192, B @ r*8192+4096

    const int tid  = threadIdx.x;
    const int wave = tid >> 6;
    const int lane = tid & 63;

    // XCD swizzle: 6 n-blocks of one m-group share an XCD (keeps A in one L2)
    const int id   = blockIdx.x;
    const int xcd  = id & 7;
    const int slot = id >> 3;
    const int bmg  = slot / 6;
    const int bm   = xcd * 16 + bmg;
    const int bn   = slot - bmg * 6;
    const int m0   = bm << 7;
    const int n0   = bn << 7;

    // padding-bool upload-width detection (256-B probe, in-bounds both ways)
    const bool u8mode = __any(pad_in[lane] > 1u);

    // ---- DMA staging map: wave w stages rows [32w,32w+32) of A and of B ----
    // instr = 16 rows x 4 granules(16B); lane = 4*row + pos, granule g = pos ^ (row&3)
    const int rl = lane >> 2;
    const int g  = (lane & 3) ^ (rl & 3);
    const unsigned short* aga0 = A  + (size_t)(m0 + wave * 32 + rl) * 768 + g * 8;
    const unsigned short* aga1 = aga0 + (size_t)16 * 768;
    const unsigned short* bga0 = Bt + (size_t)(n0 + wave * 32 + rl) * 768 + g * 8;
    const unsigned short* bga1 = bga0 + (size_t)16 * 768;
    const int l0 = wave * 32 * 32;            // LDS shorts offset of wave's chunk 0
    const int l1 = l0 + 16 * 32;

    // ---- fragment map: swizzled pos = quad ^ (fr&3) -> b128 reads at bank floor
    const int fr      = lane & 15;
    const int quad    = lane >> 4;
    const int row_off = (wave & 1) << 6;
    const int col_off = (wave >> 1) << 6;
    const int afro = (row_off + fr) * 32 + ((quad ^ (fr & 3)) << 3);
    const int bfro = (col_off + fr) * 32 + ((quad ^ (fr & 3)) << 3) + 4096;

    f4_t acc[4][4] = {};

    auto issue = [&](int t, int b) {
        unsigned short* Ab = (unsigned short*)LDS + b * 8192;
        unsigned short* Bb = Ab + 4096;
        const int ko = t * 32;
        async_ld16(aga0 + ko, Ab + l0);
        async_ld16(aga1 + ko, Ab + l1);
        async_ld16(bga0 + ko, Bb + l0);
        async_ld16(bga1 + ko, Bb + l1);
    };

    issue(0, 0);                              // prime: tiles 0,1 in flight (8 loads)
    issue(1, 1);

    int bi = 0;
    for (int t = 0; t < 24; ++t) {
        // wait for tile t's 4 DMAs only; t+1 (and later t+2) stay outstanding
        if (t < 23) __builtin_amdgcn_s_waitcnt(0xF74);   // vmcnt(4), lgkm/exp untouched
        else        __builtin_amdgcn_s_waitcnt(0xF70);   // vmcnt(0)
        __builtin_amdgcn_sched_barrier(0);
        __builtin_amdgcn_s_barrier();
        __builtin_amdgcn_sched_barrier(0);
        if (t < 22) {                         // issue after barrier: WAR-safe on ring
            int nb = bi + 2; if (nb >= 3) nb -= 3;
            issue(t + 2, nb);
        }
        const unsigned short* Ar = LDS + bi * 8192 + afro;
        const unsigned short* Br = LDS + bi * 8192 + bfro;
        bfrag_t a[4], b[4];
#pragma unroll
        for (int i = 0; i < 4; ++i) a[i] = *(const bfrag_t*)(Ar + i * 512);
#pragma unroll
        for (int i = 0; i < 4; ++i) b[i] = *(const bfrag_t*)(Br + i * 512);
#pragma unroll
        for (int mi = 0; mi < 4; ++mi)
#pragma unroll
            for (int ni = 0; ni < 4; ++ni)
                acc[mi][ni] = __builtin_amdgcn_mfma_f32_16x16x32_bf16(
                    a[mi], b[ni], acc[mi][ni], 0, 0, 0);
        if (++bi == 3) bi = 0;
    }

    // ---- epilogue: C/D layout col = lane&15, row = quad*4 + reg (verified) ----
    const unsigned char* pad8 = (const unsigned char*)pad_in;
    const int colbase = n0 + col_off;
#pragma unroll
    for (int mi = 0; mi < 4; ++mi) {
#pragma unroll
        for (int reg = 0; reg < 4; ++reg) {
            int gm  = m0 + row_off + mi * 16 + (quad << 2) + reg;
            int xid = pos_ids[2 * gm];
            int yid = pos_ids[2 * gm + 1];
            xid = xid < 0 ? 0 : xid;
            yid = yid < 0 ? 0 : yid;
            bool p = u8mode ? (pad8[gm] != 0) : (pad_in[gm] != 0u);
            const float* t0 = pos_table + (size_t)xid * 768 + colbase;
            const float* t1 = pos_table + (size_t)(V_POS + yid) * 768 + colbase;
            float* orow = out + (size_t)gm * 768 + colbase;
#pragma unroll
            for (int ni = 0; ni < 4; ++ni) {
                int cc = ni * 16 + fr;
                float pos = p ? 0.f : (t0[cc] + t1[cc]);
                orow[cc] = acc[mi][ni][reg] + pos;
            }
        }
    }
}

extern "C" void kernel_launch(void* const* d_in, const int* in_sizes, int n_in,
                              void* d_out, int out_size, void* d_ws, size_t ws_size,
                              hipStream_t stream) {
    const float*        px  = (const float*)d_in[0];        // (16,3,512,512)
    const float*        wp  = (const float*)d_in[1];        // (768,768)
    const float*        pt  = (const float*)d_in[2];        // (2,10240,768)
    const int*          pid = (const int*)d_in[3];          // (16,1024,2)
    const unsigned int* pad = (const unsigned int*)d_in[4]; // (16,1024) bool

    unsigned short* A  = (unsigned short*)d_ws;             // 25.2 MB bf16
    unsigned short* Wb = A + (size_t)16384 * 768;           // 1.18 MB bf16

    prep_kernel<<<800, 256, 0, stream>>>(px, wp, A, Wb);
    gemm_kernel<<<768, 256, 0, stream>>>(A, Wb, pid, pad, pt, (float*)d_out);
}

// Round 6
// 173.969 us; speedup vs baseline: 1.0300x; 1.0300x over previous
//
#include <hip/hip_runtime.h>
#include <stdint.h>

// Gemma4PatchEmbed round 6: barrier-free K-loop.
// bpack: w_proj fp32 -> bf16 packed in MFMA-fragment-linear order (1KB per
//        32n x 16k chunk; a wave's fragment load = lane*16B contiguous dwordx4).
// fused: block = 64 M-rows x 768 N, 512 thr, 1 block/CU (grid 256).
//        phase 1: pixels -> bf16 -> LDS A (64 x 768, stride 776; fragment
//        reads at the exact ds_read_b128 bank floor). ONE __syncthreads.
//        phase 2: 48 k16-steps of 2x3 v_mfma_f32_32x32x16_bf16 per wave;
//        A from stable LDS, B from global packed (L2-resident) -- no barriers,
//        no LDS-DMA hazards, compiler pipelines freely. Fused pos-gather epilogue.

typedef __attribute__((ext_vector_type(8))) short bfrag_t;        // MFMA A/B operand
typedef __attribute__((ext_vector_type(16))) float f16acc;         // 32x32 MFMA C/D
typedef __attribute__((ext_vector_type(8))) unsigned short u16x8;
typedef __attribute__((ext_vector_type(4))) unsigned short u16x4;

#define V_POS 10240
#define RSA 776     // LDS A row stride in shorts: 1552 B -> +4 dword-banks/row,
                    // fragment b128 reads land balanced at the 8-cyc floor

__device__ __forceinline__ unsigned short f2bf(float f) {
    unsigned int u = __float_as_uint(f);
    u += 0x7fffu + ((u >> 16) & 1u);          // RNE fp32 -> bf16
    return (unsigned short)(u >> 16);
}

// ---------------------------------------------------------------------------
// Kernel 1: pack w_proj into fragment-linear bf16.
// chunk (n32, k16) = 1024 B; element: lane holds w_proj[n32*32 + (lane&31)]
// [k16*16 + (lane>>5)*8 + j], j<8. 288 blocks x 256 thr.
// ---------------------------------------------------------------------------
__global__ __launch_bounds__(256) void bpack_kernel(
    const float* __restrict__ wp, unsigned short* __restrict__ Bp)
{
    int u     = blockIdx.x * 256 + threadIdx.x;   // 0..73727
    int chunk = u >> 6;                           // 0..1151
    int lane  = u & 63;
    int n32   = chunk / 48;
    int k16   = chunk - n32 * 48;
    int n     = (n32 << 5) + (lane & 31);
    int k     = (k16 << 4) + ((lane >> 5) << 3);
    const float* s = wp + (size_t)n * 768 + k;
    float4 v0 = *(const float4*)s;
    float4 v1 = *(const float4*)(s + 4);
    u16x8 o;
    o[0] = f2bf(v0.x); o[1] = f2bf(v0.y); o[2] = f2bf(v0.z); o[3] = f2bf(v0.w);
    o[4] = f2bf(v1.x); o[5] = f2bf(v1.y); o[6] = f2bf(v1.z); o[7] = f2bf(v1.w);
    *(u16x8*)(Bp + (size_t)chunk * 512 + (lane << 3)) = o;
}

// ---------------------------------------------------------------------------
// Kernel 2: fused patch-extract + GEMM + pos-embed. 256 blocks x 512 threads.
// ---------------------------------------------------------------------------
__global__ __launch_bounds__(512, 2) void fused_kernel(
    const float* __restrict__ px, const unsigned short* __restrict__ Bp,
    const int* __restrict__ pos_ids, const unsigned int* __restrict__ pad_in,
    const float* __restrict__ pos_table, float* __restrict__ out)
{
    __shared__ unsigned short As[64 * RSA];   // 99328 B

    const int tid  = threadIdx.x;
    const int wave = tid >> 6;                // 0..7
    const int lane = tid & 63;
    const int bid  = blockIdx.x;
    const int m0   = bid << 6;                // 64 patch rows per block
    const int img  = bid >> 4;
    const int prow = bid & 15;                // image pixel rows 32*prow .. +32

    // ---------------- phase 1: pixels -> bf16 A-tile in LDS ----------------
    // 3 ch x 32 rows x 512 w = 12288 float4, 24 per thread, fully coalesced.
    const float* base = px + ((size_t)img * 3 * 512 + (size_t)prow * 32) * 512;
#pragma unroll 6
    for (int it = 0; it < 24; ++it) {
        int idx = it * 512 + tid;
        int c   = idx >> 12;                  // 4096 f4 per channel
        int rem = idx & 4095;
        int hl  = rem >> 7;                   // 0..31 image row within region
        int w4  = rem & 127;
        float4 v = *(const float4*)(base + (size_t)c * 262144 + hl * 512 + (w4 << 2));
        int r = ((hl >> 4) << 5) + (w4 >> 2); // A row: patch-row-pair * 32 + patch-col
        int k = (c << 8) + ((hl & 15) << 4) + ((w4 & 3) << 2);
        u16x4 o;
        o[0] = f2bf(2.f * v.x - 1.f);
        o[1] = f2bf(2.f * v.y - 1.f);
        o[2] = f2bf(2.f * v.z - 1.f);
        o[3] = f2bf(2.f * v.w - 1.f);
        *(u16x4*)&As[r * RSA + k] = o;
    }
    __syncthreads();                          // the only barrier in the kernel

    // padding-bool upload-width probe (256 B, in-bounds either way)
    const bool u8mode = __any(pad_in[lane] > 1u);

    // ---------------- phase 2: barrier-free MFMA loop ----------------------
    // A frag: lane holds A[m = lane&31][k = k16*16 + (lane>>5)*8 + j]
    // B frag: packed chunk ((wave*3+nt)*48 + k16)*512 + lane*8
    const unsigned short* afrag = As + (size_t)(lane & 31) * RSA + ((lane >> 5) << 3);
    const unsigned short* bbase = Bp + (size_t)(wave * 3) * 48 * 512 + (lane << 3);

    f16acc acc[2][3] = {};

#pragma unroll 4
    for (int k16 = 0; k16 < 48; ++k16) {
        const unsigned short* ak = afrag + (k16 << 4);
        bfrag_t a0 = *(const bfrag_t*)(ak);
        bfrag_t a1 = *(const bfrag_t*)(ak + 32 * RSA);
        const unsigned short* bk = bbase + (size_t)k16 * 512;
        bfrag_t b0 = *(const bfrag_t*)(bk);
        bfrag_t b1 = *(const bfrag_t*)(bk + 48 * 512);
        bfrag_t b2 = *(const bfrag_t*)(bk + 96 * 512);
        acc[0][0] = __builtin_amdgcn_mfma_f32_32x32x16_bf16(a0, b0, acc[0][0], 0, 0, 0);
        acc[0][1] = __builtin_amdgcn_mfma_f32_32x32x16_bf16(a0, b1, acc[0][1], 0, 0, 0);
        acc[0][2] = __builtin_amdgcn_mfma_f32_32x32x16_bf16(a0, b2, acc[0][2], 0, 0, 0);
        acc[1][0] = __builtin_amdgcn_mfma_f32_32x32x16_bf16(a1, b0, acc[1][0], 0, 0, 0);
        acc[1][1] = __builtin_amdgcn_mfma_f32_32x32x16_bf16(a1, b1, acc[1][1], 0, 0, 0);
        acc[1][2] = __builtin_amdgcn_mfma_f32_32x32x16_bf16(a1, b2, acc[1][2], 0, 0, 0);
    }

    // ---- epilogue: 32x32 C/D layout col=lane&31, row=(r&3)+8*(r>>2)+4*(lane>>5)
    const unsigned char* pad8 = (const unsigned char*)pad_in;
    const int cl  = lane & 31;
    const int h4  = (lane >> 5) << 2;
#pragma unroll
    for (int mt = 0; mt < 2; ++mt) {
#pragma unroll
        for (int r = 0; r < 16; ++r) {
            int row = (mt << 5) + (r & 3) + ((r >> 2) << 3) + h4;
            int gm  = m0 + row;
            int xid = pos_ids[2 * gm];
            int yid = pos_ids[2 * gm + 1];
            xid = xid < 0 ? 0 : xid;
            yid = yid < 0 ? 0 : yid;
            bool p = u8mode ? (pad8[gm] != 0) : (pad_in[gm] != 0u);
            const float* t0 = pos_table + (size_t)xid * 768;
            const float* t1 = pos_table + (size_t)(V_POS + yid) * 768;
            float* orow = out + (size_t)gm * 768;
#pragma unroll
            for (int nt = 0; nt < 3; ++nt) {
                int col = wave * 96 + (nt << 5) + cl;
                float pos = p ? 0.f : (t0[col] + t1[col]);
                orow[col] = acc[mt][nt][r] + pos;
            }
        }
    }
}

extern "C" void kernel_launch(void* const* d_in, const int* in_sizes, int n_in,
                              void* d_out, int out_size, void* d_ws, size_t ws_size,
                              hipStream_t stream) {
    const float*        px  = (const float*)d_in[0];        // (16,3,512,512)
    const float*        wp  = (const float*)d_in[1];        // (768,768)
    const float*        pt  = (const float*)d_in[2];        // (2,10240,768)
    const int*          pid = (const int*)d_in[3];          // (16,1024,2)
    const unsigned int* pad = (const unsigned int*)d_in[4]; // (16,1024) bool

    unsigned short* Bp = (unsigned short*)d_ws;             // 1.18 MB packed bf16

    bpack_kernel<<<288, 256, 0, stream>>>(wp, Bp);
    fused_kernel<<<256, 512, 0, stream>>>(px, Bp, pid, pad, pt, (float*)d_out);
}

// Round 7
// 173.542 us; speedup vs baseline: 1.0326x; 1.0025x over previous
//
#include <hip/hip_runtime.h>
#include <stdint.h>

// Gemma4PatchEmbed round 7: round-6 structure + explicit software pipeline in
// the barrier-free K-loop.
// bpack: w_proj fp32 -> bf16 packed fragment-linear (1KB per 32n x 16k chunk).
// fused: block = 64 M-rows x 768 N, 512 thr, grid 256 (1 block/CU).
//        phase 1: pixels -> bf16 -> LDS A (stride 776). ONE __syncthreads.
//        phase 2: two-buffer register rotation -- fragments for k16+2/k16+3
//        issued before the mfmas that wait on k16/k16+1 (~400-cyc lead > L2
//        latency); 6x v_mfma_f32_32x32x16_bf16 per k16 per wave.
//        Fused pos-gather epilogue.

typedef __attribute__((ext_vector_type(8))) short bfrag_t;        // MFMA A/B operand
typedef __attribute__((ext_vector_type(16))) float f16acc;         // 32x32 MFMA C/D
typedef __attribute__((ext_vector_type(8))) unsigned short u16x8;
typedef __attribute__((ext_vector_type(4))) unsigned short u16x4;

#define V_POS 10240
#define RSA 776     // LDS A row stride in shorts: +4 dword-banks/row -> b128 floor

__device__ __forceinline__ unsigned short f2bf(float f) {
    unsigned int u = __float_as_uint(f);
    u += 0x7fffu + ((u >> 16) & 1u);          // RNE fp32 -> bf16
    return (unsigned short)(u >> 16);
}

// ---------------------------------------------------------------------------
// Kernel 1: pack w_proj into fragment-linear bf16.
// chunk (n32, k16) = 1024 B; lane holds w_proj[n32*32 + (lane&31)]
// [k16*16 + (lane>>5)*8 + j], j<8. 288 blocks x 256 thr.
// ---------------------------------------------------------------------------
__global__ __launch_bounds__(256) void bpack_kernel(
    const float* __restrict__ wp, unsigned short* __restrict__ Bp)
{
    int u     = blockIdx.x * 256 + threadIdx.x;   // 0..73727
    int chunk = u >> 6;                           // 0..1151
    int lane  = u & 63;
    int n32   = chunk / 48;
    int k16   = chunk - n32 * 48;
    int n     = (n32 << 5) + (lane & 31);
    int k     = (k16 << 4) + ((lane >> 5) << 3);
    const float* s = wp + (size_t)n * 768 + k;
    float4 v0 = *(const float4*)s;
    float4 v1 = *(const float4*)(s + 4);
    u16x8 o;
    o[0] = f2bf(v0.x); o[1] = f2bf(v0.y); o[2] = f2bf(v0.z); o[3] = f2bf(v0.w);
    o[4] = f2bf(v1.x); o[5] = f2bf(v1.y); o[6] = f2bf(v1.z); o[7] = f2bf(v1.w);
    *(u16x8*)(Bp + (size_t)chunk * 512 + (lane << 3)) = o;
}

// ---------------------------------------------------------------------------
// Kernel 2: fused patch-extract + GEMM + pos-embed. 256 blocks x 512 threads.
// ---------------------------------------------------------------------------
__global__ __launch_bounds__(512, 2) void fused_kernel(
    const float* __restrict__ px, const unsigned short* __restrict__ Bp,
    const int* __restrict__ pos_ids, const unsigned int* __restrict__ pad_in,
    const float* __restrict__ pos_table, float* __restrict__ out)
{
    __shared__ unsigned short As[64 * RSA];   // 99328 B

    const int tid  = threadIdx.x;
    const int wave = tid >> 6;                // 0..7
    const int lane = tid & 63;
    const int bid  = blockIdx.x;
    const int m0   = bid << 6;                // 64 patch rows per block
    const int img  = bid >> 4;
    const int prow = bid & 15;                // image pixel rows 32*prow .. +32

    // ---------------- phase 1: pixels -> bf16 A-tile in LDS ----------------
    const float* base = px + ((size_t)img * 3 * 512 + (size_t)prow * 32) * 512;
#pragma unroll 6
    for (int it = 0; it < 24; ++it) {
        int idx = it * 512 + tid;
        int c   = idx >> 12;                  // 4096 f4 per channel
        int rem = idx & 4095;
        int hl  = rem >> 7;                   // 0..31 image row within region
        int w4  = rem & 127;
        float4 v = *(const float4*)(base + (size_t)c * 262144 + hl * 512 + (w4 << 2));
        int r = ((hl >> 4) << 5) + (w4 >> 2); // A row
        int k = (c << 8) + ((hl & 15) << 4) + ((w4 & 3) << 2);
        u16x4 o;
        o[0] = f2bf(2.f * v.x - 1.f);
        o[1] = f2bf(2.f * v.y - 1.f);
        o[2] = f2bf(2.f * v.z - 1.f);
        o[3] = f2bf(2.f * v.w - 1.f);
        *(u16x4*)&As[r * RSA + k] = o;
    }
    __syncthreads();                          // the only barrier in the kernel

    // padding-bool upload-width probe (256 B, in-bounds either way)
    const bool u8mode = __any(pad_in[lane] > 1u);

    // ---------------- phase 2: software-pipelined barrier-free loop --------
    const unsigned short* afrag = As + (size_t)(lane & 31) * RSA + ((lane >> 5) << 3);
    const unsigned short* bbase = Bp + (size_t)(wave * 3) * 48 * 512 + (lane << 3);

    f16acc acc[2][3] = {};

    bfrag_t aC0, aC1, bC0, bC1, bC2;          // buffer C: even k16
    bfrag_t aN0, aN1, bN0, bN1, bN2;          // buffer N: odd  k16

#define LDA(k, r0, r1) { const unsigned short* ak_ = afrag + ((k) << 4);      \
        r0 = *(const bfrag_t*)(ak_);                                          \
        r1 = *(const bfrag_t*)(ak_ + 32 * RSA); }
#define LDB(k, r0, r1, r2) { const unsigned short* bk_ = bbase + (size_t)(k) * 512; \
        r0 = *(const bfrag_t*)(bk_);                                          \
        r1 = *(const bfrag_t*)(bk_ + 48 * 512);                               \
        r2 = *(const bfrag_t*)(bk_ + 96 * 512); }
#define MFMA6(a0, a1, b0, b1, b2)                                             \
        acc[0][0] = __builtin_amdgcn_mfma_f32_32x32x16_bf16(a0, b0, acc[0][0], 0, 0, 0); \
        acc[0][1] = __builtin_amdgcn_mfma_f32_32x32x16_bf16(a0, b1, acc[0][1], 0, 0, 0); \
        acc[0][2] = __builtin_amdgcn_mfma_f32_32x32x16_bf16(a0, b2, acc[0][2], 0, 0, 0); \
        acc[1][0] = __builtin_amdgcn_mfma_f32_32x32x16_bf16(a1, b0, acc[1][0], 0, 0, 0); \
        acc[1][1] = __builtin_amdgcn_mfma_f32_32x32x16_bf16(a1, b1, acc[1][1], 0, 0, 0); \
        acc[1][2] = __builtin_amdgcn_mfma_f32_32x32x16_bf16(a1, b2, acc[1][2], 0, 0, 0);

    LDA(0, aC0, aC1); LDB(0, bC0, bC1, bC2);  // prologue: k16 = 0, 1 in regs
    LDA(1, aN0, aN1); LDB(1, bN0, bN1, bN2);

    for (int k16 = 0; k16 < 48; k16 += 2) {
        // consume C (k16), refill C with k16+2 (issued ~2 k-steps before use)
        MFMA6(aC0, aC1, bC0, bC1, bC2);
        if (k16 + 2 < 48) { LDA(k16 + 2, aC0, aC1); LDB(k16 + 2, bC0, bC1, bC2); }
        // consume N (k16+1), refill N with k16+3
        MFMA6(aN0, aN1, bN0, bN1, bN2);
        if (k16 + 3 < 48) { LDA(k16 + 3, aN0, aN1); LDB(k16 + 3, bN0, bN1, bN2); }
    }
#undef LDA
#undef LDB
#undef MFMA6

    // ---- epilogue: 32x32 C/D layout col=lane&31, row=(r&3)+8*(r>>2)+4*(lane>>5)
    const unsigned char* pad8 = (const unsigned char*)pad_in;
    const int cl  = lane & 31;
    const int h4  = (lane >> 5) << 2;
#pragma unroll
    for (int mt = 0; mt < 2; ++mt) {
#pragma unroll
        for (int r = 0; r < 16; ++r) {
            int row = (mt << 5) + (r & 3) + ((r >> 2) << 3) + h4;
            int gm  = m0 + row;
            int xid = pos_ids[2 * gm];
            int yid = pos_ids[2 * gm + 1];
            xid = xid < 0 ? 0 : xid;
            yid = yid < 0 ? 0 : yid;
            bool p = u8mode ? (pad8[gm] != 0) : (pad_in[gm] != 0u);
            const float* t0 = pos_table + (size_t)xid * 768;
            const float* t1 = pos_table + (size_t)(V_POS + yid) * 768;
            float* orow = out + (size_t)gm * 768;
#pragma unroll
            for (int nt = 0; nt < 3; ++nt) {
                int col = wave * 96 + (nt << 5) + cl;
                float pos = p ? 0.f : (t0[col] + t1[col]);
                orow[col] = acc[mt][nt][r] + pos;
            }
        }
    }
}

extern "C" void kernel_launch(void* const* d_in, const int* in_sizes, int n_in,
                              void* d_out, int out_size, void* d_ws, size_t ws_size,
                              hipStream_t stream) {
    const float*        px  = (const float*)d_in[0];        // (16,3,512,512)
    const float*        wp  = (const float*)d_in[1];        // (768,768)
    const float*        pt  = (const float*)d_in[2];        // (2,10240,768)
    const int*          pid = (const int*)d_in[3];          // (16,1024,2)
    const unsigned int* pad = (const unsigned int*)d_in[4]; // (16,1024) bool

    unsigned short* Bp = (unsigned short*)d_ws;             // 1.18 MB packed bf16

    bpack_kernel<<<288, 256, 0, stream>>>(wp, Bp);
    fused_kernel<<<256, 512, 0, stream>>>(px, Bp, pid, pad, pt, (float*)d_out);
}